// Round 5
// baseline (11062.189 us; speedup 1.0000x reference)
//
#include <hip/hip_runtime.h>
#include <cmath>

// 11-layer stacked LSTM, S=512, B=256, H=106 (gate 424). One block/batch row.
// R5 vs R4 (single lever): pass every packed weight register through an empty
// asm volatile("":"+v") after loading. R1-R4 all showed VGPR_Count~80-88 for
// kernels naming 112+ weight VGPRs: the invariant-marked weight loads were
// REMATERIALIZED into the 512-step loop by the register allocator, making
// every round L2-BW-bound (~190KB/CU/step) instead of weight-resident.
// The opaque asm def is un-rematerializable -> allocator must keep VGPRs.

namespace {
constexpr int H   = 106;
constexpr int G4  = 424;
constexpr int SEQ = 512;
constexpr int BB  = 256;
constexpr int XP  = 112;   // padded f16 row stride

using half2v = __attribute__((ext_vector_type(2))) _Float16;

__device__ __forceinline__ float d2(int w, int u, float acc) {
    return __builtin_amdgcn_fdot2(__builtin_bit_cast(half2v, w),
                                  __builtin_bit_cast(half2v, u), acc, false);
}
__device__ __forceinline__ float fast_sigmoid(float x) {
    return 1.0f / (1.0f + __expf(-x));
}
__device__ __forceinline__ float fast_tanh(float x) {
    float t = __expf(2.0f * x);
    return 1.0f - 2.0f / (t + 1.0f);
}
__device__ __forceinline__ int packpair(const float* p, int k, int kmax) {
    unsigned short lo = 0, hi = 0;
    if (k < kmax)     lo = __builtin_bit_cast(unsigned short, (_Float16)p[k]);
    if (k + 1 < kmax) hi = __builtin_bit_cast(unsigned short, (_Float16)p[k + 1]);
    return (int)(((unsigned)hi << 16) | (unsigned)lo);
}
__device__ __forceinline__ int4 pack8(const float* p, int q, int kmax) {
    return make_int4(packpair(p, 8 * q, kmax),     packpair(p, 8 * q + 2, kmax),
                     packpair(p, 8 * q + 4, kmax), packpair(p, 8 * q + 6, kmax));
}

// Opaque def: value can no longer be rematerialized from its defining load.
#define OPQ4(v) asm volatile("" : "+v"(v.x), "+v"(v.y), "+v"(v.z), "+v"(v.w))

#define L14(X) X(0) X(1) X(2) X(3) X(4) X(5) X(6) X(7) X(8) X(9) X(10) X(11) X(12) X(13)
#define L53(X) X(0) X(1) X(2) X(3) X(4) X(5) X(6) X(7) X(8) X(9) X(10) X(11) X(12) \
    X(13) X(14) X(15) X(16) X(17) X(18) X(19) X(20) X(21) X(22) X(23) X(24) X(25) \
    X(26) X(27) X(28) X(29) X(30) X(31) X(32) X(33) X(34) X(35) X(36) X(37) X(38) \
    X(39) X(40) X(41) X(42) X(43) X(44) X(45) X(46) X(47) X(48) X(49) X(50) X(51) X(52)

// noise f32 (S*B,100) -> x16 (S*B,112) f16, pads zero. 4 rows/block.
__global__ __launch_bounds__(512)
void to_f16(const float* __restrict__ src, _Float16* __restrict__ dst) {
    size_t row = (size_t)blockIdx.x * 4 + (threadIdx.x >> 7);
    int k = threadIdx.x & 127;
    if (k < XP) {
        float v = (k < 100) ? src[row * 100 + k] : 0.0f;
        dst[row * XP + k] = (_Float16)v;
    }
}

template <int K_IN, bool LAST>
__global__ __launch_bounds__(512)
__attribute__((amdgpu_waves_per_eu(2)))
void lstm_layer(const _Float16* x16,             // (S,B,112) f16 — NOT restrict
                float* __restrict__ yout,        // (S,B,106) f32, LAST only
                _Float16* xnext,                 // (S,B,112) f16, !LAST only
                const float* __restrict__ Wih,   // (424,K_IN)
                const float* __restrict__ Whh,   // (424,106)
                const float* __restrict__ bih,   // (424)
                const float* __restrict__ bhh)   // (424)
{
    const int b = blockIdx.x;
    const int j = threadIdx.x;
    const int lane = threadIdx.x & 63;

    __shared__ __align__(8) _Float16 su16[128];  // h_t f16, pads zero
    __shared__ float gatesLDS[G4];

    // ---- weights: 28 named int4 (f16-pair packed), made un-rematerializable ----
#define DW(Q) int4 wx##Q{}; int4 wh##Q{};
    L14(DW)
#undef DW
    float bias = 0.0f;
    const int gid = j / H;
    if (j < G4) {
        const float* px = Wih + (size_t)j * K_IN;
        const float* ph = Whh + (size_t)j * H;
#define LW(Q) wx##Q = pack8(px, Q, K_IN); wh##Q = pack8(ph, Q, H); \
              OPQ4(wx##Q); OPQ4(wh##Q);
        L14(LW)
#undef LW
        bias = bih[j] + bhh[j];
        asm volatile("" : "+v"(bias));
    }

    if (j < 128) su16[j] = (_Float16)0.0f;
    float c = 0.0f;
    const int4* xrow0 = (const int4*)(x16 + (size_t)b * XP);
    float*      ybase = LAST ? (yout + (size_t)b * H) : nullptr;
    _Float16*   xnbase = LAST ? nullptr : (xnext + (size_t)b * XP);
    __syncthreads();

    for (int s = 0; s < SEQ; ++s) {
        // ---- x_t: 14 broadcast VMEM int4 loads (issue early) ----
        const int4* xp4 = xrow0 + (size_t)s * (BB * XP / 8);
#define XL(Q) const int4 xv##Q = xp4[Q];
        L14(XL)
#undef XL
        // ---- h_t: 1 ds_read_b32 + 53 readlanes -> SGPRs ----
        const int hv = ((const int*)su16)[lane];
#define RL(i) const int hrl##i = __builtin_amdgcn_readlane(hv, i);
        L53(RL)
#undef RL

        if (j < G4) {
            float a0 = 0.f, a1 = 0.f, a2 = 0.f, a3 = 0.f;
            // h-part: 53 dot2 (SGPR second operand)
#define HD(Q, A, B, C, D) \
            a0 = d2(wh##Q.x, hrl##A, a0); a1 = d2(wh##Q.y, hrl##B, a1); \
            a2 = d2(wh##Q.z, hrl##C, a2); a3 = d2(wh##Q.w, hrl##D, a3);
            HD(0, 0, 1, 2, 3)    HD(1, 4, 5, 6, 7)    HD(2, 8, 9, 10, 11)
            HD(3, 12, 13, 14, 15) HD(4, 16, 17, 18, 19) HD(5, 20, 21, 22, 23)
            HD(6, 24, 25, 26, 27) HD(7, 28, 29, 30, 31) HD(8, 32, 33, 34, 35)
            HD(9, 36, 37, 38, 39) HD(10, 40, 41, 42, 43) HD(11, 44, 45, 46, 47)
            HD(12, 48, 49, 50, 51)
#undef HD
            a0 = d2(wh13.x, hrl52, a0);
            // x-part: 56 dot2 (VGPR operands; pad weights are zero)
#define XD(Q) \
            a0 = d2(wx##Q.x, xv##Q.x, a0); a1 = d2(wx##Q.y, xv##Q.y, a1); \
            a2 = d2(wx##Q.z, xv##Q.z, a2); a3 = d2(wx##Q.w, xv##Q.w, a3);
            L14(XD)
#undef XD
            float g = bias + ((a0 + a1) + (a2 + a3));
            gatesLDS[j] = (gid == 2) ? fast_tanh(g) : fast_sigmoid(g);
        }
        __syncthreads();

        // ---- phase B: state update, h broadcast, output ----
        if (j < H) {
            float gi = gatesLDS[j];
            float gf = gatesLDS[H + j];
            float gg = gatesLDS[2 * H + j];
            float go = gatesLDS[3 * H + j];
            c = fmaf(gf, c, gi * gg);
            float h = go * fast_tanh(c);
            su16[j] = (_Float16)h;
            if (LAST) ybase[(size_t)s * BB * H + j] = h;
            else      xnbase[(size_t)s * BB * XP + j] = (_Float16)h;
        } else if (!LAST && j < XP) {
            xnbase[(size_t)s * BB * XP + j] = (_Float16)0.0f;
        }
        __syncthreads();
    }
}
}  // namespace

extern "C" void kernel_launch(void* const* d_in, const int* in_sizes, int n_in,
                              void* d_out, int out_size, void* d_ws, size_t ws_size,
                              hipStream_t stream) {
    const float* noise = (const float*)d_in[0];
    const float* W_ih0 = (const float*)d_in[1];
    const float* W_hh0 = (const float*)d_in[2];
    const float* b_ih0 = (const float*)d_in[3];
    const float* b_hh0 = (const float*)d_in[4];
    const float* W_ih  = (const float*)d_in[5];
    const float* W_hh  = (const float*)d_in[6];
    const float* b_ih  = (const float*)d_in[7];
    const float* b_hh  = (const float*)d_in[8];

    float* out = (float*)d_out;
    // f16 ping-pong: even-index X buffers in ws, odd-index in d_out region.
    _Float16* xeven = (_Float16*)d_ws;          // 29.36 MB
    _Float16* xodd  = (_Float16*)d_out;         // 29.36 MB <= 55.6 MB (f32 out)

    dim3 gridc(SEQ * BB / 4), blockc(512);
    to_f16<<<gridc, blockc, 0, stream>>>(noise, xeven);   // X0 = ws

    dim3 grid(BB), block(512);
    // L0: X0 -> X1
    lstm_layer<100, false><<<grid, block, 0, stream>>>(
        xeven, nullptr, xodd, W_ih0, W_hh0, b_ih0, b_hh0);
    // L1..L9: Xk -> Xk+1
    for (int l = 0; l < 9; ++l) {
        const _Float16* src = ((l & 1) == 0) ? xodd : xeven;
        _Float16* dst       = ((l & 1) == 0) ? xeven : xodd;
        lstm_layer<106, false><<<grid, block, 0, stream>>>(
            src, nullptr, dst,
            W_ih + (size_t)l * G4 * H, W_hh + (size_t)l * G4 * H,
            b_ih + (size_t)l * G4,     b_hh + (size_t)l * G4);
    }
    // L10 (last): X10 (= ws, even) -> f32 d_out
    lstm_layer<106, true><<<grid, block, 0, stream>>>(
        xeven, out, nullptr,
        W_ih + (size_t)9 * G4 * H, W_hh + (size_t)9 * G4 * H,
        b_ih + (size_t)9 * G4,     b_hh + (size_t)9 * G4);
}

// Round 6
// 8351.109 us; speedup vs baseline: 1.3246x; 1.3246x over previous
//
#include <hip/hip_runtime.h>
#include <cmath>

// 11-layer stacked LSTM, S=512, B=256, H=106 (gate 424). One block/batch row.
// R6 vs R5 (single lever): amdgpu_waves_per_eu(2,2). R1-R5 showed the AMDGPU
// backend targets MAX achievable occupancy (8 waves/EU -> 64 VGPR budget),
// spilling/rematerializing ~112 weight VGPRs into the 512-step loop; our grid
// is 1 block/CU so that occupancy is unreachable. Capping max waves/EU at 2
// (= exactly our 8 waves/block) gives the allocator the full 256-VGPR budget
// with no incentive to shrink below it.

namespace {
constexpr int H   = 106;
constexpr int G4  = 424;
constexpr int SEQ = 512;
constexpr int BB  = 256;
constexpr int XP  = 112;   // padded f16 row stride

using half2v = __attribute__((ext_vector_type(2))) _Float16;

__device__ __forceinline__ float d2(int w, int u, float acc) {
    return __builtin_amdgcn_fdot2(__builtin_bit_cast(half2v, w),
                                  __builtin_bit_cast(half2v, u), acc, false);
}
__device__ __forceinline__ float fast_sigmoid(float x) {
    return 1.0f / (1.0f + __expf(-x));
}
__device__ __forceinline__ float fast_tanh(float x) {
    float t = __expf(2.0f * x);
    return 1.0f - 2.0f / (t + 1.0f);
}
__device__ __forceinline__ int packpair(const float* p, int k, int kmax) {
    unsigned short lo = 0, hi = 0;
    if (k < kmax)     lo = __builtin_bit_cast(unsigned short, (_Float16)p[k]);
    if (k + 1 < kmax) hi = __builtin_bit_cast(unsigned short, (_Float16)p[k + 1]);
    return (int)(((unsigned)hi << 16) | (unsigned)lo);
}
__device__ __forceinline__ int4 pack8(const float* p, int q, int kmax) {
    return make_int4(packpair(p, 8 * q, kmax),     packpair(p, 8 * q + 2, kmax),
                     packpair(p, 8 * q + 4, kmax), packpair(p, 8 * q + 6, kmax));
}

// Pin value definition in a VGPR (un-rematerializable).
#define OPQ4(v) asm volatile("" : "+v"(v.x), "+v"(v.y), "+v"(v.z), "+v"(v.w))

#define L14(X) X(0) X(1) X(2) X(3) X(4) X(5) X(6) X(7) X(8) X(9) X(10) X(11) X(12) X(13)
#define L53(X) X(0) X(1) X(2) X(3) X(4) X(5) X(6) X(7) X(8) X(9) X(10) X(11) X(12) \
    X(13) X(14) X(15) X(16) X(17) X(18) X(19) X(20) X(21) X(22) X(23) X(24) X(25) \
    X(26) X(27) X(28) X(29) X(30) X(31) X(32) X(33) X(34) X(35) X(36) X(37) X(38) \
    X(39) X(40) X(41) X(42) X(43) X(44) X(45) X(46) X(47) X(48) X(49) X(50) X(51) X(52)

// noise f32 (S*B,100) -> x16 (S*B,112) f16, pads zero. 4 rows/block.
__global__ __launch_bounds__(512)
void to_f16(const float* __restrict__ src, _Float16* __restrict__ dst) {
    size_t row = (size_t)blockIdx.x * 4 + (threadIdx.x >> 7);
    int k = threadIdx.x & 127;
    if (k < XP) {
        float v = (k < 100) ? src[row * 100 + k] : 0.0f;
        dst[row * XP + k] = (_Float16)v;
    }
}

template <int K_IN, bool LAST>
__global__
__attribute__((amdgpu_flat_work_group_size(512, 512)))
__attribute__((amdgpu_waves_per_eu(2, 2)))
void lstm_layer(const _Float16* x16,             // (S,B,112) f16 — NOT restrict
                float* __restrict__ yout,        // (S,B,106) f32, LAST only
                _Float16* xnext,                 // (S,B,112) f16, !LAST only
                const float* __restrict__ Wih,   // (424,K_IN)
                const float* __restrict__ Whh,   // (424,106)
                const float* __restrict__ bih,   // (424)
                const float* __restrict__ bhh)   // (424)
{
    const int b = blockIdx.x;
    const int j = threadIdx.x;
    const int lane = threadIdx.x & 63;

    __shared__ __align__(8) _Float16 su16[128];  // h_t f16, pads zero
    __shared__ float gatesLDS[G4];

    // ---- weights: 28 named int4 (f16-pair packed), pinned in VGPRs ----
#define DW(Q) int4 wx##Q{}; int4 wh##Q{};
    L14(DW)
#undef DW
    float bias = 0.0f;
    const int gid = j / H;
    if (j < G4) {
        const float* px = Wih + (size_t)j * K_IN;
        const float* ph = Whh + (size_t)j * H;
#define LW(Q) wx##Q = pack8(px, Q, K_IN); wh##Q = pack8(ph, Q, H); \
              OPQ4(wx##Q); OPQ4(wh##Q);
        L14(LW)
#undef LW
        bias = bih[j] + bhh[j];
        asm volatile("" : "+v"(bias));
    }

    if (j < 128) su16[j] = (_Float16)0.0f;
    float c = 0.0f;
    const int4* xrow0 = (const int4*)(x16 + (size_t)b * XP);
    float*      ybase = LAST ? (yout + (size_t)b * H) : nullptr;
    _Float16*   xnbase = LAST ? nullptr : (xnext + (size_t)b * XP);
    __syncthreads();

    for (int s = 0; s < SEQ; ++s) {
        // ---- x_t: 14 broadcast VMEM int4 loads (issue early) ----
        const int4* xp4 = xrow0 + (size_t)s * (BB * XP / 8);
#define XL(Q) const int4 xv##Q = xp4[Q];
        L14(XL)
#undef XL
        // ---- h_t: 1 ds_read_b32 + 53 readlanes -> SGPRs ----
        const int hv = ((const int*)su16)[lane];
#define RL(i) const int hrl##i = __builtin_amdgcn_readlane(hv, i);
        L53(RL)
#undef RL

        if (j < G4) {
            float a0 = 0.f, a1 = 0.f, a2 = 0.f, a3 = 0.f;
            // h-part: 53 dot2 (SGPR second operand)
#define HD(Q, A, B, C, D) \
            a0 = d2(wh##Q.x, hrl##A, a0); a1 = d2(wh##Q.y, hrl##B, a1); \
            a2 = d2(wh##Q.z, hrl##C, a2); a3 = d2(wh##Q.w, hrl##D, a3);
            HD(0, 0, 1, 2, 3)    HD(1, 4, 5, 6, 7)    HD(2, 8, 9, 10, 11)
            HD(3, 12, 13, 14, 15) HD(4, 16, 17, 18, 19) HD(5, 20, 21, 22, 23)
            HD(6, 24, 25, 26, 27) HD(7, 28, 29, 30, 31) HD(8, 32, 33, 34, 35)
            HD(9, 36, 37, 38, 39) HD(10, 40, 41, 42, 43) HD(11, 44, 45, 46, 47)
            HD(12, 48, 49, 50, 51)
#undef HD
            a0 = d2(wh13.x, hrl52, a0);
            // x-part: 56 dot2 (VGPR operands; pad weights are zero)
#define XD(Q) \
            a0 = d2(wx##Q.x, xv##Q.x, a0); a1 = d2(wx##Q.y, xv##Q.y, a1); \
            a2 = d2(wx##Q.z, xv##Q.z, a2); a3 = d2(wx##Q.w, xv##Q.w, a3);
            L14(XD)
#undef XD
            float g = bias + ((a0 + a1) + (a2 + a3));
            gatesLDS[j] = (gid == 2) ? fast_tanh(g) : fast_sigmoid(g);
        }
        __syncthreads();

        // ---- phase B: state update, h broadcast, output ----
        if (j < H) {
            float gi = gatesLDS[j];
            float gf = gatesLDS[H + j];
            float gg = gatesLDS[2 * H + j];
            float go = gatesLDS[3 * H + j];
            c = fmaf(gf, c, gi * gg);
            float h = go * fast_tanh(c);
            su16[j] = (_Float16)h;
            if (LAST) ybase[(size_t)s * BB * H + j] = h;
            else      xnbase[(size_t)s * BB * XP + j] = (_Float16)h;
        } else if (!LAST && j < XP) {
            xnbase[(size_t)s * BB * XP + j] = (_Float16)0.0f;
        }
        __syncthreads();
    }
}
}  // namespace

extern "C" void kernel_launch(void* const* d_in, const int* in_sizes, int n_in,
                              void* d_out, int out_size, void* d_ws, size_t ws_size,
                              hipStream_t stream) {
    const float* noise = (const float*)d_in[0];
    const float* W_ih0 = (const float*)d_in[1];
    const float* W_hh0 = (const float*)d_in[2];
    const float* b_ih0 = (const float*)d_in[3];
    const float* b_hh0 = (const float*)d_in[4];
    const float* W_ih  = (const float*)d_in[5];
    const float* W_hh  = (const float*)d_in[6];
    const float* b_ih  = (const float*)d_in[7];
    const float* b_hh  = (const float*)d_in[8];

    float* out = (float*)d_out;
    // f16 ping-pong: even-index X buffers in ws, odd-index in d_out region.
    _Float16* xeven = (_Float16*)d_ws;          // 29.36 MB
    _Float16* xodd  = (_Float16*)d_out;         // 29.36 MB <= 55.6 MB (f32 out)

    dim3 gridc(SEQ * BB / 4), blockc(512);
    to_f16<<<gridc, blockc, 0, stream>>>(noise, xeven);   // X0 = ws

    dim3 grid(BB), block(512);
    // L0: X0 -> X1
    lstm_layer<100, false><<<grid, block, 0, stream>>>(
        xeven, nullptr, xodd, W_ih0, W_hh0, b_ih0, b_hh0);
    // L1..L9: Xk -> Xk+1
    for (int l = 0; l < 9; ++l) {
        const _Float16* src = ((l & 1) == 0) ? xodd : xeven;
        _Float16* dst       = ((l & 1) == 0) ? xeven : xodd;
        lstm_layer<106, false><<<grid, block, 0, stream>>>(
            src, nullptr, dst,
            W_ih + (size_t)l * G4 * H, W_hh + (size_t)l * G4 * H,
            b_ih + (size_t)l * G4,     b_hh + (size_t)l * G4);
    }
    // L10 (last): X10 (= ws, even) -> f32 d_out
    lstm_layer<106, true><<<grid, block, 0, stream>>>(
        xeven, out, nullptr,
        W_ih + (size_t)9 * G4 * H, W_hh + (size_t)9 * G4 * H,
        b_ih + (size_t)9 * G4,     b_hh + (size_t)9 * G4);
}

// Round 7
// 5394.844 us; speedup vs baseline: 2.0505x; 1.5480x over previous
//
#include <hip/hip_runtime.h>
#include <cmath>

// 11-layer stacked LSTM, S=512, B=256, H=106 (gate 424). One block/batch row.
// R7 redesign: MFMA (16x16x32 f16) with M=1.
//  - R2-R3 were LDS-broadcast-instruction-bound (189 ds_read_b128/step);
//    that floor is invariant under any dot2 re-split. MFMA broadcasts the
//    u-operand in hardware: 7 b128 per wave per step instead of 27.
//  - Weights = register-resident B-fragments, 56 VGPR/thread (14 waves x
//    2 N-tiles) -- sized UNDER the ~128-VGPR grant ceiling the allocator
//    enforced in R1-R6, so no spill/remat fight.
//  - A-frag: all 16-lane groups read the same u chunk -> every A row = u,
//    so any C row holds the gate dot (extraction robust to row-map detail).

namespace {
constexpr int H   = 106;
constexpr int G4  = 424;
constexpr int SEQ = 512;
constexpr int BB  = 256;
constexpr int XP  = 112;   // padded x width (f16)
constexpr int KP  = 224;   // u width: [x pad 112 | h pad 112] = 7 k-steps of 32
constexpr int NT  = 27;    // N-tiles of 16 gate rows (432 cols, 424 real)

using f16x8 = __attribute__((ext_vector_type(8))) _Float16;
using f32x4 = __attribute__((ext_vector_type(4))) float;

__device__ __forceinline__ float fast_sigmoid(float x) {
    return 1.0f / (1.0f + __expf(-x));
}
__device__ __forceinline__ float fast_tanh(float x) {
    float t = __expf(2.0f * x);
    return 1.0f - 2.0f / (t + 1.0f);
}

// noise f32 (S*B,100) -> x16 (S*B,112) f16, pads zero. 4 rows/block.
__global__ __launch_bounds__(512)
void to_f16(const float* __restrict__ src, _Float16* __restrict__ dst) {
    size_t row = (size_t)blockIdx.x * 4 + (threadIdx.x >> 7);
    int k = threadIdx.x & 127;
    if (k < XP) {
        float v = (k < 100) ? src[row * 100 + k] : 0.0f;
        dst[row * XP + k] = (_Float16)v;
    }
}

template <int K_IN, bool LAST>
__global__ __launch_bounds__(896)
__attribute__((amdgpu_waves_per_eu(4, 4)))   // budget 512/4 = 128 VGPR >= ask ~90
void lstm_layer(const _Float16* __restrict__ x16,  // (S,B,112) f16
                float* __restrict__ yout,          // (S,B,106) f32, LAST
                _Float16* __restrict__ xnext,      // (S,B,112) f16, !LAST
                const float* __restrict__ Wih,     // (424,K_IN)
                const float* __restrict__ Whh,     // (424,106)
                const float* __restrict__ bih,     // (424)
                const float* __restrict__ bhh)     // (424)
{
    const int b    = blockIdx.x;
    const int j    = threadIdx.x;
    const int w    = j >> 6;         // wave 0..13
    const int lane = j & 63;
    const int l16  = lane & 15;      // N-col within tile
    const int kg   = lane >> 4;      // k-chunk group 0..3

    __shared__ __align__(16) _Float16 su[KP];   // u = [x(112) | h(112)]
    __shared__ float gates[NT * 16 + 16];       // 448 (junk tail never read)

    // ---- pack B-fragments: wave w owns N-tiles t0=2w, t1=2w+1 (t1 may be junk) ----
    // lane l, k-step q, elem e: value = Wc[n][32q + 8*kg + e], n = 16t + l16.
    const int t0 = 2 * w, t1 = 2 * w + 1;
    f16x8 bf0[7], bf1[7];
    float bias0 = 0.f, bias1 = 0.f;
    {
        const int n0 = 16 * t0 + l16;
        const int n1 = 16 * t1 + l16;
        const float* pih0 = Wih + (size_t)n0 * K_IN;
        const float* phh0 = Whh + (size_t)n0 * H;
        const float* pih1 = Wih + (size_t)n1 * K_IN;
        const float* phh1 = Whh + (size_t)n1 * H;
        #pragma unroll
        for (int q = 0; q < 7; ++q) {
            f16x8 v0, v1;
            #pragma unroll
            for (int e = 0; e < 8; ++e) {
                const int k = 32 * q + 8 * kg + e;
                float a = 0.f, c = 0.f;
                if (k < XP) {
                    if (k < K_IN) {
                        if (n0 < G4) a = pih0[k];
                        if (n1 < G4) c = pih1[k];
                    }
                } else {
                    const int k2 = k - XP;
                    if (k2 < H) {
                        if (n0 < G4) a = phh0[k2];
                        if (n1 < G4) c = phh1[k2];
                    }
                }
                v0[e] = (_Float16)a;
                v1[e] = (_Float16)c;
            }
            bf0[q] = v0;
            bf1[q] = v1;
        }
        if (n0 < G4) bias0 = bih[n0] + bhh[n0];
        if (n1 < G4) bias1 = bih[n1] + bhh[n1];
    }

    // ---- init u = [x_0 | 0] ----
    if (j < KP) su[j] = (_Float16)0;
    __syncthreads();
    if (j < 56) ((int*)su)[j] = ((const int*)(x16 + (size_t)b * XP))[j];
    float c = 0.f;
    __syncthreads();

    for (int s = 0; s < SEQ; ++s) {
        // prefetch x_{s+1} (wave 2 lanes 0..55; latency hides under MFMAs)
        int pre = 0;
        const bool dopre = (s + 1 < SEQ) && (j >= 128) && (j < 184);
        if (dopre)
            pre = ((const int*)(x16 + ((size_t)(s + 1) * BB + b) * XP))[j - 128];

        // ---- A-phase: 7 k-steps, 2 MFMAs each ----
        f32x4 acc0 = {0.f, 0.f, 0.f, 0.f};
        f32x4 acc1 = {0.f, 0.f, 0.f, 0.f};
        #pragma unroll
        for (int q = 0; q < 7; ++q) {
            const f16x8 a = *reinterpret_cast<const f16x8*>(&su[32 * q + 8 * kg]);
            acc0 = __builtin_amdgcn_mfma_f32_16x16x32_f16(a, bf0[q], acc0, 0, 0, 0);
            acc1 = __builtin_amdgcn_mfma_f32_16x16x32_f16(a, bf1[q], acc1, 0, 0, 0);
        }
        // ---- extract (all C rows equal u.W_n): lanes 0..15, reg 0 ----
        if (lane < 16) {
            const int n0 = 16 * t0 + l16;
            const float g0 = acc0[0] + bias0;
            gates[n0] = (n0 >= 2 * H && n0 < 3 * H) ? fast_tanh(g0) : fast_sigmoid(g0);
            const int n1 = 16 * t1 + l16;
            const float g1 = acc1[0] + bias1;
            gates[n1] = (n1 >= 2 * H && n1 < 3 * H) ? fast_tanh(g1) : fast_sigmoid(g1);
        }
        __syncthreads();

        // ---- B-phase: state update + h into su + output + x install ----
        if (j < H) {
            const float gi = gates[j];
            const float gf = gates[H + j];
            const float gg = gates[2 * H + j];
            const float go = gates[3 * H + j];
            c = fmaf(gf, c, gi * gg);
            const float h = go * fast_tanh(c);
            su[XP + j] = (_Float16)h;
            if (LAST) yout[((size_t)s * BB + b) * H + j] = h;
            else      xnext[((size_t)s * BB + b) * XP + j] = (_Float16)h;
        } else if (!LAST && j >= H && j < XP) {
            xnext[((size_t)s * BB + b) * XP + j] = (_Float16)0;
        }
        if (dopre) ((int*)su)[j - 128] = pre;
        __syncthreads();
    }
}
}  // namespace

extern "C" void kernel_launch(void* const* d_in, const int* in_sizes, int n_in,
                              void* d_out, int out_size, void* d_ws, size_t ws_size,
                              hipStream_t stream) {
    const float* noise = (const float*)d_in[0];
    const float* W_ih0 = (const float*)d_in[1];
    const float* W_hh0 = (const float*)d_in[2];
    const float* b_ih0 = (const float*)d_in[3];
    const float* b_hh0 = (const float*)d_in[4];
    const float* W_ih  = (const float*)d_in[5];
    const float* W_hh  = (const float*)d_in[6];
    const float* b_ih  = (const float*)d_in[7];
    const float* b_hh  = (const float*)d_in[8];

    float* out = (float*)d_out;
    _Float16* xeven = (_Float16*)d_ws;    // 29.36 MB
    _Float16* xodd  = (_Float16*)d_out;   // f16 scratch inside f32 out region

    dim3 gridc(SEQ * BB / 4), blockc(512);
    to_f16<<<gridc, blockc, 0, stream>>>(noise, xeven);   // X0 = ws

    dim3 grid(BB), block(896);
    // L0: X0 -> X1
    lstm_layer<100, false><<<grid, block, 0, stream>>>(
        xeven, nullptr, xodd, W_ih0, W_hh0, b_ih0, b_hh0);
    // L1..L9
    for (int l = 0; l < 9; ++l) {
        const _Float16* src = ((l & 1) == 0) ? xodd : xeven;
        _Float16* dst       = ((l & 1) == 0) ? xeven : xodd;
        lstm_layer<106, false><<<grid, block, 0, stream>>>(
            src, nullptr, dst,
            W_ih + (size_t)l * G4 * H, W_hh + (size_t)l * G4 * H,
            b_ih + (size_t)l * G4,     b_hh + (size_t)l * G4);
    }
    // L10 (last): X10 (= ws) -> f32 d_out
    lstm_layer<106, true><<<grid, block, 0, stream>>>(
        xeven, out, nullptr,
        W_ih + (size_t)9 * G4 * H, W_hh + (size_t)9 * G4 * H,
        b_ih + (size_t)9 * G4,     b_hh + (size_t)9 * G4);
}